// Round 17
// baseline (178.688 us; speedup 1.0000x reference)
//
#include <hip/hip_runtime.h>
#include <hip/hip_bf16.h>

// Problem constants
#define BB 2
#define TT 2048
#define EE 1024
#define HH 8
// D = 64, 2D = 128 per head
#define LAMBDA_INIT 0.35550906759096928f
#define ONE_MINUS_LI 0.64449093240903072f

typedef short s16x8 __attribute__((ext_vector_type(8)));
typedef short s16x4 __attribute__((ext_vector_type(4)));
typedef float f32x4 __attribute__((ext_vector_type(4)));

#define MFMA16(a,b,c) __builtin_amdgcn_mfma_f32_16x16x32_bf16((a),(b),(c),0,0,0)

__device__ __forceinline__ short f2b(float f) {
  __hip_bfloat16 h = __float2bfloat16(f);
  return *reinterpret_cast<short*>(&h);
}

__device__ __forceinline__ void load_lds16(const void* g, void* l) {
  __builtin_amdgcn_global_load_lds(
      (const __attribute__((address_space(1))) unsigned int*)g,
      (__attribute__((address_space(3))) unsigned int*)l, 16, 0, 0);
}

// ---------------- x -> bf16 ----------------
__global__ __launch_bounds__(256) void cvt_x(const float* __restrict__ x, short* __restrict__ xb) {
  int i = blockIdx.x * 256 + threadIdx.x;
  float4 v = ((const float4*)x)[i];
  s16x4 s;
  s[0] = f2b(v.x); s[1] = f2b(v.y); s[2] = f2b(v.z); s[3] = f2b(v.w);
  ((s16x4*)xb)[i] = s;
}

// ---------------- weights -> bf16, transposed (wT[n][k]) ----------------
__global__ __launch_bounds__(256) void transpose_w(const float* __restrict__ wq, const float* __restrict__ wk,
                                                   const float* __restrict__ wv, const float* __restrict__ wo,
                                                   short* __restrict__ wT) {
  __shared__ float t[32][33];
  const int z = blockIdx.z;
  const float* src = (z == 0) ? wq : (z == 1) ? wk : (z == 2) ? wv : wo;
  const int nbase = blockIdx.x * 32, kbase = blockIdx.y * 32;
  const int tx = threadIdx.x, ty = threadIdx.y;
#pragma unroll
  for (int i = 0; i < 4; i++)
    t[ty + i * 8][tx] = src[(size_t)(kbase + ty + i * 8) * EE + nbase + tx];
  __syncthreads();
  short* dst = wT + (size_t)z * EE * EE;
#pragma unroll
  for (int i = 0; i < 4; i++)
    dst[(size_t)(nbase + ty + i * 8) * EE + kbase + tx] = f2b(t[tx][ty + i * 8]);
}

// ---------------- V (row-major) -> VT[bh][dim][token] (r5/r9-verified) ----------------
__global__ __launch_bounds__(256) void transpose_v(const short* __restrict__ Vb, short* __restrict__ VT) {
  __shared__ short t[32][33];
  const int bh = blockIdx.z, b = bh >> 3, h = bh & 7;
  const int tok0 = blockIdx.x * 32, dim0 = blockIdx.y * 32;
  const int tx = threadIdx.x, ty = threadIdx.y;
#pragma unroll
  for (int j = 0; j < 4; j++)
    t[ty + j * 8][tx] = Vb[(size_t)(b * TT + tok0 + ty + j * 8) * EE + h * 128 + dim0 + tx];
  __syncthreads();
#pragma unroll
  for (int j = 0; j < 4; j++)
    VT[((size_t)bh * 128 + dim0 + ty + j * 8) * TT + tok0 + tx] = t[tx][ty + j * 8];
}

// ---------------- lambda scalar ----------------
__global__ void lam_kernel(const float* __restrict__ lq1, const float* __restrict__ lk1,
                           const float* __restrict__ lq2, const float* __restrict__ lk2,
                           float* __restrict__ out) {
  int d = threadIdx.x;  // 64 threads = 1 wave
  float p1 = lq1[d] * lk1[d];
  float p2 = lq2[d] * lk2[d];
#pragma unroll
  for (int m = 1; m <= 32; m <<= 1) { p1 += __shfl_xor(p1, m); p2 += __shfl_xor(p2, m); }
  if (d == 0) out[0] = __expf(p1) - __expf(p2) + LAMBDA_INIT;
}

// ---------------- 128x128 bf16 MFMA GEMM core (K=1024, all strides 1024) ----------------
__device__ __forceinline__ void gemm_body(const short* __restrict__ A, const short* __restrict__ Bt,
                                          int row0, int col0, f32x4 acc[4][4],
                                          short* As, short* Bs) {
  const int tid = threadIdx.x, wv = tid >> 6, lane = tid & 63;
  const int lr = lane & 15, lg = lane >> 4;
  const int wr = wv >> 1, wc = wv & 1;
#pragma unroll
  for (int m = 0; m < 4; m++)
#pragma unroll
    for (int n = 0; n < 4; n++) acc[m][n] = (f32x4){0.f, 0.f, 0.f, 0.f};

  for (int kt = 0; kt < 1024; kt += 32) {
#pragma unroll
    for (int c = 0; c < 2; c++) {
      load_lds16((const char*)(A + (size_t)(row0 + wv * 32 + c * 16 + (lane >> 2)) * 1024 + kt) + (lane & 3) * 16,
                 (char*)As + (wv * 32 + c * 16) * 64 + lane * 16);
      load_lds16((const char*)(Bt + (size_t)(col0 + wv * 32 + c * 16 + (lane >> 2)) * 1024 + kt) + (lane & 3) * 16,
                 (char*)Bs + (wv * 32 + c * 16) * 64 + lane * 16);
    }
    __syncthreads();
    s16x8 af[4], bfr[4];
#pragma unroll
    for (int m = 0; m < 4; m++) af[m] = *(const s16x8*)&As[(wr * 64 + m * 16 + lr) * 32 + lg * 8];
#pragma unroll
    for (int n = 0; n < 4; n++) bfr[n] = *(const s16x8*)&Bs[(wc * 64 + n * 16 + lr) * 32 + lg * 8];
#pragma unroll
    for (int m = 0; m < 4; m++)
#pragma unroll
      for (int n = 0; n < 4; n++) acc[m][n] = MFMA16(af[m], bfr[n], acc[m][n]);
    __syncthreads();
  }
}

// QKV projection: x(4096x1024) @ {wq,wk,wv} -> bf16 Q,K,V (row-major, r3-verified)
__global__ __launch_bounds__(256) void gemm_qkv(const short* __restrict__ xb, const short* __restrict__ wT,
                                                short* __restrict__ Qb, short* __restrict__ Kb,
                                                short* __restrict__ Vb) {
  __shared__ short As[128 * 32];
  __shared__ short Bs[128 * 32];
  const int row0 = blockIdx.x * 128;
  const int wsel = blockIdx.y >> 3;
  const int col0 = (blockIdx.y & 7) * 128;
  const short* Bt = wT + (size_t)wsel * EE * EE;
  short* outp = (wsel == 0) ? Qb : (wsel == 1) ? Kb : Vb;
  f32x4 acc[4][4];
  gemm_body(xb, Bt, row0, col0, acc, As, Bs);
  const int lane = threadIdx.x & 63, wv = threadIdx.x >> 6;
  const int lr = lane & 15, lg = lane >> 4, wr = wv >> 1, wc = wv & 1;
#pragma unroll
  for (int m = 0; m < 4; m++)
#pragma unroll
    for (int n = 0; n < 4; n++)
#pragma unroll
      for (int r = 0; r < 4; r++) {
        int row = row0 + wr * 64 + m * 16 + lg * 4 + r;
        int col = col0 + wc * 64 + n * 16 + lr;
        outp[(size_t)row * 1024 + col] = f2b(acc[m][n][r]);
      }
}

// Output projection: anorm(4096x1024 bf16) @ wo -> d_out fp32
__global__ __launch_bounds__(256) void gemm_out(const short* __restrict__ an, const short* __restrict__ woT,
                                                float* __restrict__ C) {
  __shared__ short As[128 * 32];
  __shared__ short Bs[128 * 32];
  const int row0 = blockIdx.x * 128;
  const int col0 = blockIdx.y * 128;
  f32x4 acc[4][4];
  gemm_body(an, woT, row0, col0, acc, As, Bs);
  const int lane = threadIdx.x & 63, wv = threadIdx.x >> 6;
  const int lr = lane & 15, lg = lane >> 4, wr = wv >> 1, wc = wv & 1;
#pragma unroll
  for (int m = 0; m < 4; m++)
#pragma unroll
    for (int n = 0; n < 4; n++)
#pragma unroll
      for (int r = 0; r < 4; r++) {
        int row = row0 + wr * 64 + m * 16 + lg * 4 + r;
        int col = col0 + wc * 64 + n * 16 + lr;
        C[(size_t)row * 1024 + col] = acc[m][n][r];
      }
}

// ---------------- differential flash attention + RMS norm ----------------
// r15/r16-green per-iter body extended to 4 q-halves per wave (64 q-rows per
// block). Same 16 K/V loads per iter serve all 4 halves -> fixed per-iter cost
// amortized over 4x MFMA. kv range split across 4 waves; combine tree runs
// twice over a 4-plane LDS buffer (hf 0-1 then 2-3). Grid 512 = 16 bh x 32
// tiles, longest-first, XCD-spread; 2 blocks/CU.
__global__ __launch_bounds__(256, 1) void attn_kernel(const short* __restrict__ Q, const short* __restrict__ K,
                                                      const short* __restrict__ VT, const float* __restrict__ lamp,
                                                      const float* __restrict__ g, short* __restrict__ anorm) {
  __shared__ float ob[4][64 * 33];  // 4 planes, reused for hf-pairs
  __shared__ float lb[4][64];

  const int bid = blockIdx.x;
  const int xcd = bid & 7, slot = bid >> 3;          // 64 slots x 8 xcd
  const int bh = xcd + (slot >> 5) * 8;              // 2 bh per xcd
  const int qt = 31 - (slot & 31);                   // 32 q-tiles (64 rows), longest first
  const int b = bh >> 3, h = bh & 7;
  const int q0 = qt * 64;

  const int tid = threadIdx.x, wv = tid >> 6, lane = tid & 63;
  const int lr = lane & 15, lg = lane >> 4;

  const short* Kh = K + (size_t)b * TT * EE + h * 128;
  const short* VTh = VT + (size_t)bh * 128 * TT;

  // Q fragments for 4 q-halves (B-operand: col=lr)
  s16x8 qf1[4][2], qf2[4][2];
#pragma unroll
  for (int hf = 0; hf < 4; hf++) {
    const short* qrp = Q + ((size_t)b * TT + q0 + hf * 16 + lr) * EE + h * 128;
#pragma unroll
    for (int c = 0; c < 2; c++) {
      qf1[hf][c] = *(const s16x8*)(qrp + c * 32 + lg * 8);
      qf2[hf][c] = *(const s16x8*)(qrp + 64 + c * 32 + lg * 8);
    }
  }

  const f32x4 zero = {0.f, 0.f, 0.f, 0.f};
  f32x4 o1[4][8], o2[4][8];
#pragma unroll
  for (int hf = 0; hf < 4; hf++)
#pragma unroll
    for (int d = 0; d < 8; d++) { o1[hf][d] = zero; o2[hf][d] = zero; }
  float lp1[4] = {0.f, 0.f, 0.f, 0.f}, lp2[4] = {0.f, 0.f, 0.f, 0.f};

  const int kvend = q0 + 64;
  for (int kv0 = wv * 32; kv0 < kvend; kv0 += 128) {
    // --- V B-fragments (shared by all halves): issue early ---
    s16x8 vbf[8];
#pragma unroll
    for (int d = 0; d < 8; d++)
      vbf[d] = *(const s16x8*)(VTh + (size_t)(d * 16 + lr) * TT + kv0 + lg * 8);

    // --- K A-fragments (shared) ---
    s16x8 ka0[2], ka1[2], kc0[2], kc1[2];
#pragma unroll
    for (int kb = 0; kb < 2; kb++) {
      const short* krow = Kh + (size_t)(kv0 + kb * 16 + lr) * EE;
      ka0[kb] = *(const s16x8*)(krow + lg * 8);
      ka1[kb] = *(const s16x8*)(krow + 32 + lg * 8);
      kc0[kb] = *(const s16x8*)(krow + 64 + lg * 8);
      kc1[kb] = *(const s16x8*)(krow + 96 + lg * 8);
    }

    // --- per q-half: S^T, softmax, pack, PV ---
#pragma unroll
    for (int hf = 0; hf < 4; hf++) {
      const int qrow = q0 + hf * 16 + lr;
      f32x4 s1[2], s2[2];
#pragma unroll
      for (int kb = 0; kb < 2; kb++) {
        f32x4 t;
        t = MFMA16(ka0[kb], qf1[hf][0], zero); t = MFMA16(ka1[kb], qf1[hf][1], t); s1[kb] = t;
        t = MFMA16(kc0[kb], qf2[hf][0], zero); t = MFMA16(kc1[kb], qf2[hf][1], t); s2[kb] = t;
      }
      float p1v[8], p2v[8];
#pragma unroll
      for (int kb = 0; kb < 2; kb++)
#pragma unroll
        for (int r = 0; r < 4; r++) {
          int keyg = kv0 + kb * 16 + lg * 4 + r;
          bool ok = keyg <= qrow;
          float e1 = ok ? __expf(s1[kb][r] * 0.125f) : 0.f;
          float e2 = ok ? __expf(s2[kb][r] * 0.125f) : 0.f;
          p1v[kb * 4 + r] = e1; p2v[kb * 4 + r] = e2;
          lp1[hf] += e1; lp2[hf] += e2;
        }
      unsigned u1[4], u2[4];
#pragma unroll
      for (int q = 0; q < 4; q++) {
        asm("v_cvt_pk_bf16_f32 %0, %1, %2" : "=v"(u1[q]) : "v"(p1v[2 * q]), "v"(p1v[2 * q + 1]));
        asm("v_cvt_pk_bf16_f32 %0, %1, %2" : "=v"(u2[q]) : "v"(p2v[2 * q]), "v"(p2v[2 * q + 1]));
      }
      union { unsigned w[4]; s16x8 v; } pa1, pa2;
      const int srcbase = (lg & 1) * 32 + lr;
      const bool hi = (lg >= 2);
#pragma unroll
      for (int t = 0; t < 4; t++) {
        int src = srcbase + (t >> 1) * 16;
        unsigned a, bb2;
        a = __shfl(u1[t & 1], src); bb2 = __shfl(u1[2 + (t & 1)], src); pa1.w[t] = hi ? bb2 : a;
        a = __shfl(u2[t & 1], src); bb2 = __shfl(u2[2 + (t & 1)], src); pa2.w[t] = hi ? bb2 : a;
      }
#pragma unroll
      for (int d = 0; d < 8; d++) {
        o1[hf][d] = MFMA16(pa1.v, vbf[d], o1[hf][d]);
        o2[hf][d] = MFMA16(pa2.v, vbf[d], o2[hf][d]);
      }
    }
  }

  // --- cross-wave combine: two passes over 4-plane buffer (hf 0-1, hf 2-3) ---
#pragma unroll
  for (int hs = 0; hs < 2; hs++) {
    const int h0 = hs * 2, h1 = hs * 2 + 1;
    for (int w = 3; w >= 1; --w) {
      if (wv == w) {
#pragma unroll
        for (int d = 0; d < 8; d++)
#pragma unroll
          for (int r = 0; r < 4; r++) {
            ob[0][lane * 33 + d * 4 + r] = o1[h0][d][r];
            ob[1][lane * 33 + d * 4 + r] = o2[h0][d][r];
            ob[2][lane * 33 + d * 4 + r] = o1[h1][d][r];
            ob[3][lane * 33 + d * 4 + r] = o2[h1][d][r];
          }
        lb[0][lane] = lp1[h0]; lb[1][lane] = lp2[h0]; lb[2][lane] = lp1[h1]; lb[3][lane] = lp2[h1];
      }
      __syncthreads();
      if (wv == w - 1) {
#pragma unroll
        for (int d = 0; d < 8; d++)
#pragma unroll
          for (int r = 0; r < 4; r++) {
            o1[h0][d][r] += ob[0][lane * 33 + d * 4 + r];
            o2[h0][d][r] += ob[1][lane * 33 + d * 4 + r];
            o1[h1][d][r] += ob[2][lane * 33 + d * 4 + r];
            o2[h1][d][r] += ob[3][lane * 33 + d * 4 + r];
          }
        lp1[h0] += lb[0][lane]; lp2[h0] += lb[1][lane]; lp1[h1] += lb[2][lane]; lp2[h1] += lb[3][lane];
      }
      __syncthreads();
    }
  }

  if (wv != 0) return;

  // --- epilogue (wave 0): 4 halves, r13-verbatim per half ---
  const float lam = lamp[0];
#pragma unroll
  for (int hf = 0; hf < 4; hf++) {
    float l1 = lp1[hf], l2 = lp2[hf];
    const int rbase = q0 + hf * 16;

    l1 += __shfl_xor(l1, 16); l1 += __shfl_xor(l1, 32);
    l2 += __shfl_xor(l2, 16); l2 += __shfl_xor(l2, 32);

    f32x4 i1, i2;
#pragma unroll
    for (int r = 0; r < 4; r++) {
      i1[r] = 1.f / __shfl(l1, lg * 4 + r);
      i2[r] = 1.f / __shfl(l2, lg * 4 + r);
    }
    f32x4 a[8];
    float ss[4] = {0.f, 0.f, 0.f, 0.f};
#pragma unroll
    for (int d = 0; d < 8; d++) {
      a[d] = o1[hf][d] * i1 - (lam * o2[hf][d]) * i2;
#pragma unroll
      for (int r = 0; r < 4; r++) ss[r] += a[d][r] * a[d][r];
    }
#pragma unroll
    for (int r = 0; r < 4; r++) {
      ss[r] += __shfl_xor(ss[r], 1);
      ss[r] += __shfl_xor(ss[r], 2);
      ss[r] += __shfl_xor(ss[r], 4);
      ss[r] += __shfl_xor(ss[r], 8);
    }
    f32x4 rs;
#pragma unroll
    for (int r = 0; r < 4; r++) rs[r] = rsqrtf(ss[r] * (1.f / 128.f) + 1e-5f) * ONE_MINUS_LI;
#pragma unroll
    for (int d = 0; d < 8; d++) {
      float gv = g[d * 16 + lr];
#pragma unroll
      for (int r = 0; r < 4; r++) {
        int row = rbase + lg * 4 + r;
        anorm[((size_t)b * TT + row) * 1024 + h * 128 + d * 16 + lr] = f2b(a[d][r] * rs[r] * gv);
      }
    }
  }
}

extern "C" void kernel_launch(void* const* d_in, const int* in_sizes, int n_in,
                              void* d_out, int out_size, void* d_ws, size_t ws_size,
                              hipStream_t stream) {
  const float* x   = (const float*)d_in[0];
  const float* wq  = (const float*)d_in[1];
  const float* wk  = (const float*)d_in[2];
  const float* wv  = (const float*)d_in[3];
  const float* wo  = (const float*)d_in[4];
  const float* lq1 = (const float*)d_in[5];
  const float* lk1 = (const float*)d_in[6];
  const float* lq2 = (const float*)d_in[7];
  const float* lk2 = (const float*)d_in[8];
  const float* g   = (const float*)d_in[9];

  // Workspace layout (40 MB + 4 B), aliasing dead regions (r9/r13-verified):
  //   [0,8)   MB : xb (bf16 x)        -- dead after gemm_qkv; reused as VT
  //   [8,16)  MB : wT
  //   [16,24) MB : Qb   [24,32) MB : Kb
  //   [32,40) MB : Vb (row-major V)   -- dead after transpose_v; reused as an
  //   40 MB       : lamf (4 B)
  char* ws = (char*)d_ws;
  short* xb  = (short*)(ws);
  short* wT  = (short*)(ws + ((size_t)8 << 20));
  short* Qb  = (short*)(ws + ((size_t)16 << 20));
  short* Kb  = (short*)(ws + ((size_t)24 << 20));
  short* Vb  = (short*)(ws + ((size_t)32 << 20));
  short* VT  = xb;   // alias: xb dead once gemm_qkv has consumed it
  short* an  = Vb;   // alias: Vb dead once transpose_v has consumed it
  float* lamf = (float*)(ws + ((size_t)40 << 20));

  cvt_x<<<4096, 256, 0, stream>>>(x, xb);
  transpose_w<<<dim3(32, 32, 4), dim3(32, 8), 0, stream>>>(wq, wk, wv, wo, wT);
  lam_kernel<<<1, 64, 0, stream>>>(lq1, lk1, lq2, lk2, lamf);
  gemm_qkv<<<dim3(32, 24), 256, 0, stream>>>(xb, wT, Qb, Kb, Vb);
  transpose_v<<<dim3(64, 4, 16), dim3(32, 8), 0, stream>>>(Vb, VT);
  attn_kernel<<<512, 256, 0, stream>>>(Qb, Kb, VT, lamf, g, an);
  gemm_out<<<dim3(32, 8), 256, 0, stream>>>(an, wT + (size_t)3 * EE * EE, (float*)d_out);
}

// Round 20
// 157.022 us; speedup vs baseline: 1.1380x; 1.1380x over previous
//
#include <hip/hip_runtime.h>
#include <hip/hip_bf16.h>

// Problem constants
#define BB 2
#define TT 2048
#define EE 1024
#define HH 8
// D = 64, 2D = 128 per head
#define LAMBDA_INIT 0.35550906759096928f
#define ONE_MINUS_LI 0.64449093240903072f

typedef short s16x8 __attribute__((ext_vector_type(8)));
typedef short s16x4 __attribute__((ext_vector_type(4)));
typedef float f32x4 __attribute__((ext_vector_type(4)));

#define MFMA16(a,b,c) __builtin_amdgcn_mfma_f32_16x16x32_bf16((a),(b),(c),0,0,0)

__device__ __forceinline__ short f2b(float f) {
  __hip_bfloat16 h = __float2bfloat16(f);
  return *reinterpret_cast<short*>(&h);
}

__device__ __forceinline__ void load_lds16(const void* g, void* l) {
  __builtin_amdgcn_global_load_lds(
      (const __attribute__((address_space(1))) unsigned int*)g,
      (__attribute__((address_space(3))) unsigned int*)l, 16, 0, 0);
}

// ---------------- x -> bf16 ----------------
__global__ __launch_bounds__(256) void cvt_x(const float* __restrict__ x, short* __restrict__ xb) {
  int i = blockIdx.x * 256 + threadIdx.x;
  float4 v = ((const float4*)x)[i];
  s16x4 s;
  s[0] = f2b(v.x); s[1] = f2b(v.y); s[2] = f2b(v.z); s[3] = f2b(v.w);
  ((s16x4*)xb)[i] = s;
}

// ---------------- weights -> bf16, transposed (wT[n][k]) ----------------
__global__ __launch_bounds__(256) void transpose_w(const float* __restrict__ wq, const float* __restrict__ wk,
                                                   const float* __restrict__ wv, const float* __restrict__ wo,
                                                   short* __restrict__ wT) {
  __shared__ float t[32][33];
  const int z = blockIdx.z;
  const float* src = (z == 0) ? wq : (z == 1) ? wk : (z == 2) ? wv : wo;
  const int nbase = blockIdx.x * 32, kbase = blockIdx.y * 32;
  const int tx = threadIdx.x, ty = threadIdx.y;
#pragma unroll
  for (int i = 0; i < 4; i++)
    t[ty + i * 8][tx] = src[(size_t)(kbase + ty + i * 8) * EE + nbase + tx];
  __syncthreads();
  short* dst = wT + (size_t)z * EE * EE;
#pragma unroll
  for (int i = 0; i < 4; i++)
    dst[(size_t)(nbase + ty + i * 8) * EE + kbase + tx] = f2b(t[tx][ty + i * 8]);
}

// ---------------- V (row-major) -> VT[bh][dim][token] (r5/r9-verified) ----------------
__global__ __launch_bounds__(256) void transpose_v(const short* __restrict__ Vb, short* __restrict__ VT) {
  __shared__ short t[32][33];
  const int bh = blockIdx.z, b = bh >> 3, h = bh & 7;
  const int tok0 = blockIdx.x * 32, dim0 = blockIdx.y * 32;
  const int tx = threadIdx.x, ty = threadIdx.y;
#pragma unroll
  for (int j = 0; j < 4; j++)
    t[ty + j * 8][tx] = Vb[(size_t)(b * TT + tok0 + ty + j * 8) * EE + h * 128 + dim0 + tx];
  __syncthreads();
#pragma unroll
  for (int j = 0; j < 4; j++)
    VT[((size_t)bh * 128 + dim0 + ty + j * 8) * TT + tok0 + tx] = t[tx][ty + j * 8];
}

// ---------------- lambda scalar ----------------
__global__ void lam_kernel(const float* __restrict__ lq1, const float* __restrict__ lk1,
                           const float* __restrict__ lq2, const float* __restrict__ lk2,
                           float* __restrict__ out) {
  int d = threadIdx.x;  // 64 threads = 1 wave
  float p1 = lq1[d] * lk1[d];
  float p2 = lq2[d] * lk2[d];
#pragma unroll
  for (int m = 1; m <= 32; m <<= 1) { p1 += __shfl_xor(p1, m); p2 += __shfl_xor(p2, m); }
  if (d == 0) out[0] = __expf(p1) - __expf(p2) + LAMBDA_INIT;
}

// ---------------- 128x128 bf16 MFMA GEMM core (K=1024, all strides 1024) ----------------
__device__ __forceinline__ void gemm_body(const short* __restrict__ A, const short* __restrict__ Bt,
                                          int row0, int col0, f32x4 acc[4][4],
                                          short* As, short* Bs) {
  const int tid = threadIdx.x, wv = tid >> 6, lane = tid & 63;
  const int lr = lane & 15, lg = lane >> 4;
  const int wr = wv >> 1, wc = wv & 1;
#pragma unroll
  for (int m = 0; m < 4; m++)
#pragma unroll
    for (int n = 0; n < 4; n++) acc[m][n] = (f32x4){0.f, 0.f, 0.f, 0.f};

  for (int kt = 0; kt < 1024; kt += 32) {
#pragma unroll
    for (int c = 0; c < 2; c++) {
      load_lds16((const char*)(A + (size_t)(row0 + wv * 32 + c * 16 + (lane >> 2)) * 1024 + kt) + (lane & 3) * 16,
                 (char*)As + (wv * 32 + c * 16) * 64 + lane * 16);
      load_lds16((const char*)(Bt + (size_t)(col0 + wv * 32 + c * 16 + (lane >> 2)) * 1024 + kt) + (lane & 3) * 16,
                 (char*)Bs + (wv * 32 + c * 16) * 64 + lane * 16);
    }
    __syncthreads();
    s16x8 af[4], bfr[4];
#pragma unroll
    for (int m = 0; m < 4; m++) af[m] = *(const s16x8*)&As[(wr * 64 + m * 16 + lr) * 32 + lg * 8];
#pragma unroll
    for (int n = 0; n < 4; n++) bfr[n] = *(const s16x8*)&Bs[(wc * 64 + n * 16 + lr) * 32 + lg * 8];
#pragma unroll
    for (int m = 0; m < 4; m++)
#pragma unroll
      for (int n = 0; n < 4; n++) acc[m][n] = MFMA16(af[m], bfr[n], acc[m][n]);
    __syncthreads();
  }
}

// QKV projection: x(4096x1024) @ {wq,wk,wv} -> bf16 Q,K,V (row-major, r3-verified)
__global__ __launch_bounds__(256) void gemm_qkv(const short* __restrict__ xb, const short* __restrict__ wT,
                                                short* __restrict__ Qb, short* __restrict__ Kb,
                                                short* __restrict__ Vb) {
  __shared__ short As[128 * 32];
  __shared__ short Bs[128 * 32];
  const int row0 = blockIdx.x * 128;
  const int wsel = blockIdx.y >> 3;
  const int col0 = (blockIdx.y & 7) * 128;
  const short* Bt = wT + (size_t)wsel * EE * EE;
  short* outp = (wsel == 0) ? Qb : (wsel == 1) ? Kb : Vb;
  f32x4 acc[4][4];
  gemm_body(xb, Bt, row0, col0, acc, As, Bs);
  const int lane = threadIdx.x & 63, wv = threadIdx.x >> 6;
  const int lr = lane & 15, lg = lane >> 4, wr = wv >> 1, wc = wv & 1;
#pragma unroll
  for (int m = 0; m < 4; m++)
#pragma unroll
    for (int n = 0; n < 4; n++)
#pragma unroll
      for (int r = 0; r < 4; r++) {
        int row = row0 + wr * 64 + m * 16 + lg * 4 + r;
        int col = col0 + wc * 64 + n * 16 + lr;
        outp[(size_t)row * 1024 + col] = f2b(acc[m][n][r]);
      }
}

// Output projection: anorm(4096x1024 bf16) @ wo -> d_out fp32
__global__ __launch_bounds__(256) void gemm_out(const short* __restrict__ an, const short* __restrict__ woT,
                                                float* __restrict__ C) {
  __shared__ short As[128 * 32];
  __shared__ short Bs[128 * 32];
  const int row0 = blockIdx.x * 128;
  const int col0 = blockIdx.y * 128;
  f32x4 acc[4][4];
  gemm_body(an, woT, row0, col0, acc, As, Bs);
  const int lane = threadIdx.x & 63, wv = threadIdx.x >> 6;
  const int lr = lane & 15, lg = lane >> 4, wr = wv >> 1, wc = wv & 1;
#pragma unroll
  for (int m = 0; m < 4; m++)
#pragma unroll
    for (int n = 0; n < 4; n++)
#pragma unroll
      for (int r = 0; r < 4; r++) {
        int row = row0 + wr * 64 + m * 16 + lg * 4 + r;
        int col = col0 + wc * 64 + n * 16 + lr;
        C[(size_t)row * 1024 + col] = acc[m][n][r];
      }
}

// ---------------- differential flash attention + RMS norm ----------------
// r16-green structure verbatim (2 q-halves/wave, complementary-pair 2-phase,
// 4-wave kv-split, static-max). ONLY change vs r16: s_setprio(1) around the
// two MFMA clusters (T5) -- waves drift into different phases (no intra-loop
// barriers), so the CU scheduler can favor MFMA-issuing waves.
__global__ __launch_bounds__(256, 2) void attn_kernel(const short* __restrict__ Q, const short* __restrict__ K,
                                                      const short* __restrict__ VT, const float* __restrict__ lamp,
                                                      const float* __restrict__ g, short* __restrict__ anorm) {
  __shared__ float ob[4][64 * 33];  // 4 planes (o1L,o2L,o1H,o2H), stride 33
  __shared__ float lb[4][64];

  const int bid = blockIdx.x;
  const int xcd = bid & 7, slot2 = bid >> 3;         // 64 slots x 8 xcd
  const int bh = xcd + (slot2 >> 5) * 8;             // 2 bh per xcd
  const int pair = slot2 & 31;                       // 32 complementary pairs
  const int b = bh >> 3, h = bh & 7;

  const int tid = threadIdx.x, wv = tid >> 6, lane = tid & 63;
  const int lr = lane & 15, lg = lane >> 4;

  const short* Kh = K + (size_t)b * TT * EE + h * 128;
  const short* VTh = VT + (size_t)bh * 128 * TT;
  const float lam = lamp[0];

  for (int phase = 0; phase < 2; phase++) {
    const int qt = phase == 0 ? (63 - pair) : pair;  // long tile first
    const int q0 = qt * 32;
    const int qrowL = q0 + lr, qrowH = q0 + 16 + lr;

    // Q fragments for both q-halves (B-operand: col=lr)
    const short* qrpL = Q + ((size_t)b * TT + qrowL) * EE + h * 128;
    const short* qrpH = Q + ((size_t)b * TT + qrowH) * EE + h * 128;
    s16x8 qA1[2], qA2[2], qB1[2], qB2[2];
#pragma unroll
    for (int c = 0; c < 2; c++) {
      qA1[c] = *(const s16x8*)(qrpL + c * 32 + lg * 8);
      qA2[c] = *(const s16x8*)(qrpL + 64 + c * 32 + lg * 8);
      qB1[c] = *(const s16x8*)(qrpH + c * 32 + lg * 8);
      qB2[c] = *(const s16x8*)(qrpH + 64 + c * 32 + lg * 8);
    }

    const f32x4 zero = {0.f, 0.f, 0.f, 0.f};
    f32x4 o1L[8], o2L[8], o1H[8], o2H[8];
#pragma unroll
    for (int d = 0; d < 8; d++) { o1L[d] = zero; o2L[d] = zero; o1H[d] = zero; o2H[d] = zero; }
    float lp1L = 0.f, lp2L = 0.f, lp1H = 0.f, lp2H = 0.f;

    const int kvend = q0 + 32;
    for (int kv0 = wv * 32; kv0 < kvend; kv0 += 128) {
      // --- V B-fragments (shared by both q-halves): issue early ---
      s16x8 vbf[8];
#pragma unroll
      for (int d = 0; d < 8; d++)
        vbf[d] = *(const s16x8*)(VTh + (size_t)(d * 16 + lr) * TT + kv0 + lg * 8);

      // --- K A-fragments (shared); S^T for lo and hi halves ---
      f32x4 s1L[2], s2L[2], s1H[2], s2H[2];
      __builtin_amdgcn_s_setprio(1);
#pragma unroll
      for (int kb = 0; kb < 2; kb++) {
        const short* krow = Kh + (size_t)(kv0 + kb * 16 + lr) * EE;
        s16x8 ka0 = *(const s16x8*)(krow + lg * 8);
        s16x8 ka1 = *(const s16x8*)(krow + 32 + lg * 8);
        s16x8 kb0 = *(const s16x8*)(krow + 64 + lg * 8);
        s16x8 kb1 = *(const s16x8*)(krow + 96 + lg * 8);
        f32x4 t;
        t = MFMA16(ka0, qA1[0], zero); t = MFMA16(ka1, qA1[1], t); s1L[kb] = t;
        t = MFMA16(kb0, qA2[0], zero); t = MFMA16(kb1, qA2[1], t); s2L[kb] = t;
        t = MFMA16(ka0, qB1[0], zero); t = MFMA16(ka1, qB1[1], t); s1H[kb] = t;
        t = MFMA16(kb0, qB2[0], zero); t = MFMA16(kb1, qB2[1], t); s2H[kb] = t;
      }
      __builtin_amdgcn_s_setprio(0);

      // --- static-max softmax for both halves ---
      float p1L[8], p2L[8], p1H[8], p2H[8];
#pragma unroll
      for (int kb = 0; kb < 2; kb++)
#pragma unroll
        for (int r = 0; r < 4; r++) {
          int keyg = kv0 + kb * 16 + lg * 4 + r;
          bool okL = keyg <= qrowL, okH = keyg <= qrowH;
          float e1L = okL ? __expf(s1L[kb][r] * 0.125f) : 0.f;
          float e2L = okL ? __expf(s2L[kb][r] * 0.125f) : 0.f;
          float e1H = okH ? __expf(s1H[kb][r] * 0.125f) : 0.f;
          float e2H = okH ? __expf(s2H[kb][r] * 0.125f) : 0.f;
          p1L[kb * 4 + r] = e1L; p2L[kb * 4 + r] = e2L;
          p1H[kb * 4 + r] = e1H; p2H[kb * 4 + r] = e2H;
          lp1L += e1L; lp2L += e2L; lp1H += e1H; lp2H += e2H;
        }

      // --- pack+redistribute P -> PV A-fragments (both halves) ---
      const int srcbase = (lg & 1) * 32 + lr;
      const bool hi = (lg >= 2);
      union { unsigned w[4]; s16x8 v; } pa1L, pa2L, pa1H, pa2H;
      {
        unsigned u1[4], u2[4], u3[4], u4[4];
#pragma unroll
        for (int q = 0; q < 4; q++) {
          asm("v_cvt_pk_bf16_f32 %0, %1, %2" : "=v"(u1[q]) : "v"(p1L[2 * q]), "v"(p1L[2 * q + 1]));
          asm("v_cvt_pk_bf16_f32 %0, %1, %2" : "=v"(u2[q]) : "v"(p2L[2 * q]), "v"(p2L[2 * q + 1]));
          asm("v_cvt_pk_bf16_f32 %0, %1, %2" : "=v"(u3[q]) : "v"(p1H[2 * q]), "v"(p1H[2 * q + 1]));
          asm("v_cvt_pk_bf16_f32 %0, %1, %2" : "=v"(u4[q]) : "v"(p2H[2 * q]), "v"(p2H[2 * q + 1]));
        }
#pragma unroll
        for (int t = 0; t < 4; t++) {
          int src = srcbase + (t >> 1) * 16;
          unsigned a, bb2;
          a = __shfl(u1[t & 1], src); bb2 = __shfl(u1[2 + (t & 1)], src); pa1L.w[t] = hi ? bb2 : a;
          a = __shfl(u2[t & 1], src); bb2 = __shfl(u2[2 + (t & 1)], src); pa2L.w[t] = hi ? bb2 : a;
          a = __shfl(u3[t & 1], src); bb2 = __shfl(u3[2 + (t & 1)], src); pa1H.w[t] = hi ? bb2 : a;
          a = __shfl(u4[t & 1], src); bb2 = __shfl(u4[2 + (t & 1)], src); pa2H.w[t] = hi ? bb2 : a;
        }
      }

      // --- PV accumulate (shared vbf) ---
      __builtin_amdgcn_s_setprio(1);
#pragma unroll
      for (int d = 0; d < 8; d++) {
        o1L[d] = MFMA16(pa1L.v, vbf[d], o1L[d]);
        o2L[d] = MFMA16(pa2L.v, vbf[d], o2L[d]);
        o1H[d] = MFMA16(pa1H.v, vbf[d], o1H[d]);
        o2H[d] = MFMA16(pa2H.v, vbf[d], o2H[d]);
      }
      __builtin_amdgcn_s_setprio(0);
    }

    // --- cross-wave combine: waves 3->2->1->0, 4 planes ---
    for (int w = 3; w >= 1; --w) {
      if (wv == w) {
#pragma unroll
        for (int d = 0; d < 8; d++)
#pragma unroll
          for (int r = 0; r < 4; r++) {
            ob[0][lane * 33 + d * 4 + r] = o1L[d][r];
            ob[1][lane * 33 + d * 4 + r] = o2L[d][r];
            ob[2][lane * 33 + d * 4 + r] = o1H[d][r];
            ob[3][lane * 33 + d * 4 + r] = o2H[d][r];
          }
        lb[0][lane] = lp1L; lb[1][lane] = lp2L; lb[2][lane] = lp1H; lb[3][lane] = lp2H;
      }
      __syncthreads();
      if (wv == w - 1) {
#pragma unroll
        for (int d = 0; d < 8; d++)
#pragma unroll
          for (int r = 0; r < 4; r++) {
            o1L[d][r] += ob[0][lane * 33 + d * 4 + r];
            o2L[d][r] += ob[1][lane * 33 + d * 4 + r];
            o1H[d][r] += ob[2][lane * 33 + d * 4 + r];
            o2H[d][r] += ob[3][lane * 33 + d * 4 + r];
          }
        lp1L += lb[0][lane]; lp2L += lb[1][lane]; lp1H += lb[2][lane]; lp2H += lb[3][lane];
      }
      __syncthreads();
    }

    // --- epilogue (wave 0): both halves, r13-verbatim per half ---
    if (wv == 0) {
#pragma unroll
      for (int half = 0; half < 2; half++) {
        float l1 = half ? lp1H : lp1L, l2 = half ? lp2H : lp2L;
        f32x4* o1 = half ? o1H : o1L;
        f32x4* o2 = half ? o2H : o2L;
        const int rbase = q0 + half * 16;

        l1 += __shfl_xor(l1, 16); l1 += __shfl_xor(l1, 32);
        l2 += __shfl_xor(l2, 16); l2 += __shfl_xor(l2, 32);

        f32x4 i1, i2;
#pragma unroll
        for (int r = 0; r < 4; r++) {
          i1[r] = 1.f / __shfl(l1, lg * 4 + r);
          i2[r] = 1.f / __shfl(l2, lg * 4 + r);
        }
        f32x4 a[8];
        float ss[4] = {0.f, 0.f, 0.f, 0.f};
#pragma unroll
        for (int d = 0; d < 8; d++) {
          a[d] = o1[d] * i1 - (lam * o2[d]) * i2;
#pragma unroll
          for (int r = 0; r < 4; r++) ss[r] += a[d][r] * a[d][r];
        }
#pragma unroll
        for (int r = 0; r < 4; r++) {
          ss[r] += __shfl_xor(ss[r], 1);
          ss[r] += __shfl_xor(ss[r], 2);
          ss[r] += __shfl_xor(ss[r], 4);
          ss[r] += __shfl_xor(ss[r], 8);
        }
        f32x4 rs;
#pragma unroll
        for (int r = 0; r < 4; r++) rs[r] = rsqrtf(ss[r] * (1.f / 128.f) + 1e-5f) * ONE_MINUS_LI;
#pragma unroll
        for (int d = 0; d < 8; d++) {
          float gv = g[d * 16 + lr];
#pragma unroll
          for (int r = 0; r < 4; r++) {
            int row = rbase + lg * 4 + r;
            anorm[((size_t)b * TT + row) * 1024 + h * 128 + d * 16 + lr] = f2b(a[d][r] * rs[r] * gv);
          }
        }
      }
    }
    __syncthreads();  // wave0 epilogue done before next phase reuses ob/lb
  }
}

extern "C" void kernel_launch(void* const* d_in, const int* in_sizes, int n_in,
                              void* d_out, int out_size, void* d_ws, size_t ws_size,
                              hipStream_t stream) {
  const float* x   = (const float*)d_in[0];
  const float* wq  = (const float*)d_in[1];
  const float* wk  = (const float*)d_in[2];
  const float* wv  = (const float*)d_in[3];
  const float* wo  = (const float*)d_in[4];
  const float* lq1 = (const float*)d_in[5];
  const float* lk1 = (const float*)d_in[6];
  const float* lq2 = (const float*)d_in[7];
  const float* lk2 = (const float*)d_in[8];
  const float* g   = (const float*)d_in[9];

  // Workspace layout (40 MB + 4 B), aliasing dead regions (r9/r13-verified):
  //   [0,8)   MB : xb (bf16 x)        -- dead after gemm_qkv; reused as VT
  //   [8,16)  MB : wT
  //   [16,24) MB : Qb   [24,32) MB : Kb
  //   [32,40) MB : Vb (row-major V)   -- dead after transpose_v; reused as an
  //   40 MB       : lamf (4 B)
  char* ws = (char*)d_ws;
  short* xb  = (short*)(ws);
  short* wT  = (short*)(ws + ((size_t)8 << 20));
  short* Qb  = (short*)(ws + ((size_t)16 << 20));
  short* Kb  = (short*)(ws + ((size_t)24 << 20));
  short* Vb  = (short*)(ws + ((size_t)32 << 20));
  short* VT  = xb;   // alias: xb dead once gemm_qkv has consumed it
  short* an  = Vb;   // alias: Vb dead once transpose_v has consumed it
  float* lamf = (float*)(ws + ((size_t)40 << 20));

  cvt_x<<<4096, 256, 0, stream>>>(x, xb);
  transpose_w<<<dim3(32, 32, 4), dim3(32, 8), 0, stream>>>(wq, wk, wv, wo, wT);
  lam_kernel<<<1, 64, 0, stream>>>(lq1, lk1, lq2, lk2, lamf);
  gemm_qkv<<<dim3(32, 24), 256, 0, stream>>>(xb, wT, Qb, Kb, Vb);
  transpose_v<<<dim3(64, 4, 16), dim3(32, 8), 0, stream>>>(Vb, VT);
  attn_kernel<<<512, 256, 0, stream>>>(Qb, Kb, VT, lamf, g, an);
  gemm_out<<<dim3(32, 8), 256, 0, stream>>>(an, wT + (size_t)3 * EE * EE, (float*)d_out);
}

// Round 21
// 152.440 us; speedup vs baseline: 1.1722x; 1.0301x over previous
//
#include <hip/hip_runtime.h>
#include <hip/hip_bf16.h>

// Problem constants
#define BB 2
#define TT 2048
#define EE 1024
#define HH 8
// D = 64, 2D = 128 per head
#define LAMBDA_INIT 0.35550906759096928f
#define ONE_MINUS_LI 0.64449093240903072f

typedef short s16x8 __attribute__((ext_vector_type(8)));
typedef short s16x4 __attribute__((ext_vector_type(4)));
typedef float f32x4 __attribute__((ext_vector_type(4)));

#define MFMA16(a,b,c) __builtin_amdgcn_mfma_f32_16x16x32_bf16((a),(b),(c),0,0,0)

__device__ __forceinline__ short f2b(float f) {
  __hip_bfloat16 h = __float2bfloat16(f);
  return *reinterpret_cast<short*>(&h);
}

__device__ __forceinline__ void load_lds16(const void* g, void* l) {
  __builtin_amdgcn_global_load_lds(
      (const __attribute__((address_space(1))) unsigned int*)g,
      (__attribute__((address_space(3))) unsigned int*)l, 16, 0, 0);
}

// ---------------- x -> bf16 ----------------
__global__ __launch_bounds__(256) void cvt_x(const float* __restrict__ x, short* __restrict__ xb) {
  int i = blockIdx.x * 256 + threadIdx.x;
  float4 v = ((const float4*)x)[i];
  s16x4 s;
  s[0] = f2b(v.x); s[1] = f2b(v.y); s[2] = f2b(v.z); s[3] = f2b(v.w);
  ((s16x4*)xb)[i] = s;
}

// ---------------- weights -> bf16, transposed (wT[n][k]) ----------------
__global__ __launch_bounds__(256) void transpose_w(const float* __restrict__ wq, const float* __restrict__ wk,
                                                   const float* __restrict__ wv, const float* __restrict__ wo,
                                                   short* __restrict__ wT) {
  __shared__ float t[32][33];
  const int z = blockIdx.z;
  const float* src = (z == 0) ? wq : (z == 1) ? wk : (z == 2) ? wv : wo;
  const int nbase = blockIdx.x * 32, kbase = blockIdx.y * 32;
  const int tx = threadIdx.x, ty = threadIdx.y;
#pragma unroll
  for (int i = 0; i < 4; i++)
    t[ty + i * 8][tx] = src[(size_t)(kbase + ty + i * 8) * EE + nbase + tx];
  __syncthreads();
  short* dst = wT + (size_t)z * EE * EE;
#pragma unroll
  for (int i = 0; i < 4; i++)
    dst[(size_t)(nbase + ty + i * 8) * EE + kbase + tx] = f2b(t[tx][ty + i * 8]);
}

// ---------------- lambda scalar ----------------
__global__ void lam_kernel(const float* __restrict__ lq1, const float* __restrict__ lk1,
                           const float* __restrict__ lq2, const float* __restrict__ lk2,
                           float* __restrict__ out) {
  int d = threadIdx.x;  // 64 threads = 1 wave
  float p1 = lq1[d] * lk1[d];
  float p2 = lq2[d] * lk2[d];
#pragma unroll
  for (int m = 1; m <= 32; m <<= 1) { p1 += __shfl_xor(p1, m); p2 += __shfl_xor(p2, m); }
  if (d == 0) out[0] = __expf(p1) - __expf(p2) + LAMBDA_INIT;
}

// ---------------- 128x128 bf16 MFMA GEMM core (K=1024, all strides 1024) ----------------
__device__ __forceinline__ void gemm_body(const short* __restrict__ A, const short* __restrict__ Bt,
                                          int row0, int col0, f32x4 acc[4][4],
                                          short* As, short* Bs) {
  const int tid = threadIdx.x, wv = tid >> 6, lane = tid & 63;
  const int lr = lane & 15, lg = lane >> 4;
  const int wr = wv >> 1, wc = wv & 1;
#pragma unroll
  for (int m = 0; m < 4; m++)
#pragma unroll
    for (int n = 0; n < 4; n++) acc[m][n] = (f32x4){0.f, 0.f, 0.f, 0.f};

  for (int kt = 0; kt < 1024; kt += 32) {
#pragma unroll
    for (int c = 0; c < 2; c++) {
      load_lds16((const char*)(A + (size_t)(row0 + wv * 32 + c * 16 + (lane >> 2)) * 1024 + kt) + (lane & 3) * 16,
                 (char*)As + (wv * 32 + c * 16) * 64 + lane * 16);
      load_lds16((const char*)(Bt + (size_t)(col0 + wv * 32 + c * 16 + (lane >> 2)) * 1024 + kt) + (lane & 3) * 16,
                 (char*)Bs + (wv * 32 + c * 16) * 64 + lane * 16);
    }
    __syncthreads();
    s16x8 af[4], bfr[4];
#pragma unroll
    for (int m = 0; m < 4; m++) af[m] = *(const s16x8*)&As[(wr * 64 + m * 16 + lr) * 32 + lg * 8];
#pragma unroll
    for (int n = 0; n < 4; n++) bfr[n] = *(const s16x8*)&Bs[(wc * 64 + n * 16 + lr) * 32 + lg * 8];
#pragma unroll
    for (int m = 0; m < 4; m++)
#pragma unroll
      for (int n = 0; n < 4; n++) acc[m][n] = MFMA16(af[m], bfr[n], acc[m][n]);
    __syncthreads();
  }
}

// QKV projection. Q,K row-major; V written DIRECTLY transposed as
// VT[(b*8+h)*128 + dim][token] (r4 epilogue: acc r=0..3 = 4 consecutive
// tokens at one dim -> contiguous aligned s16x4 store).
__global__ __launch_bounds__(256) void gemm_qkv(const short* __restrict__ xb, const short* __restrict__ wT,
                                                short* __restrict__ Qb, short* __restrict__ Kb,
                                                short* __restrict__ VT) {
  __shared__ short As[128 * 32];
  __shared__ short Bs[128 * 32];
  const int row0 = blockIdx.x * 128;
  const int wsel = blockIdx.y >> 3;
  const int col0 = (blockIdx.y & 7) * 128;
  const short* Bt = wT + (size_t)wsel * EE * EE;
  f32x4 acc[4][4];
  gemm_body(xb, Bt, row0, col0, acc, As, Bs);
  const int lane = threadIdx.x & 63, wv = threadIdx.x >> 6;
  const int lr = lane & 15, lg = lane >> 4, wr = wv >> 1, wc = wv & 1;
  if (wsel < 2) {
    short* outp = (wsel == 0) ? Qb : Kb;
#pragma unroll
    for (int m = 0; m < 4; m++)
#pragma unroll
      for (int n = 0; n < 4; n++)
#pragma unroll
        for (int r = 0; r < 4; r++) {
          int row = row0 + wr * 64 + m * 16 + lg * 4 + r;
          int col = col0 + wc * 64 + n * 16 + lr;
          outp[(size_t)row * 1024 + col] = f2b(acc[m][n][r]);
        }
  } else {
    // V: transpose on the fly. row -> (b, token), col -> (h, dim).
#pragma unroll
    for (int m = 0; m < 4; m++)
#pragma unroll
      for (int n = 0; n < 4; n++) {
        int row = row0 + wr * 64 + m * 16 + lg * 4;  // 4 consecutive tokens
        int col = col0 + wc * 64 + n * 16 + lr;
        int bq = row >> 11, tok = row & 2047;
        int hh = col >> 7, dim = col & 127;
        s16x4 s;
#pragma unroll
        for (int r = 0; r < 4; r++) s[r] = f2b(acc[m][n][r]);
        *(s16x4*)&VT[((size_t)(bq * 8 + hh) * 128 + dim) * 2048 + tok] = s;
      }
  }
}

// Output projection: anorm(4096x1024 bf16) @ wo -> d_out fp32
__global__ __launch_bounds__(256) void gemm_out(const short* __restrict__ an, const short* __restrict__ woT,
                                                float* __restrict__ C) {
  __shared__ short As[128 * 32];
  __shared__ short Bs[128 * 32];
  const int row0 = blockIdx.x * 128;
  const int col0 = blockIdx.y * 128;
  f32x4 acc[4][4];
  gemm_body(an, woT, row0, col0, acc, As, Bs);
  const int lane = threadIdx.x & 63, wv = threadIdx.x >> 6;
  const int lr = lane & 15, lg = lane >> 4, wr = wv >> 1, wc = wv & 1;
#pragma unroll
  for (int m = 0; m < 4; m++)
#pragma unroll
    for (int n = 0; n < 4; n++)
#pragma unroll
      for (int r = 0; r < 4; r++) {
        int row = row0 + wr * 64 + m * 16 + lg * 4 + r;
        int col = col0 + wc * 64 + n * 16 + lr;
        C[(size_t)row * 1024 + col] = acc[m][n][r];
      }
}

// ---------------- differential flash attention + RMS norm ----------------
// r16-green verbatim (2 q-halves/wave, complementary-pair 2-phase, 4-wave
// kv-split, static-max, no setprio).
__global__ __launch_bounds__(256, 2) void attn_kernel(const short* __restrict__ Q, const short* __restrict__ K,
                                                      const short* __restrict__ VT, const float* __restrict__ lamp,
                                                      const float* __restrict__ g, short* __restrict__ anorm) {
  __shared__ float ob[4][64 * 33];  // 4 planes (o1L,o2L,o1H,o2H), stride 33
  __shared__ float lb[4][64];

  const int bid = blockIdx.x;
  const int xcd = bid & 7, slot2 = bid >> 3;         // 64 slots x 8 xcd
  const int bh = xcd + (slot2 >> 5) * 8;             // 2 bh per xcd
  const int pair = slot2 & 31;                       // 32 complementary pairs
  const int b = bh >> 3, h = bh & 7;

  const int tid = threadIdx.x, wv = tid >> 6, lane = tid & 63;
  const int lr = lane & 15, lg = lane >> 4;

  const short* Kh = K + (size_t)b * TT * EE + h * 128;
  const short* VTh = VT + (size_t)bh * 128 * TT;
  const float lam = lamp[0];

  for (int phase = 0; phase < 2; phase++) {
    const int qt = phase == 0 ? (63 - pair) : pair;  // long tile first
    const int q0 = qt * 32;
    const int qrowL = q0 + lr, qrowH = q0 + 16 + lr;

    // Q fragments for both q-halves (B-operand: col=lr)
    const short* qrpL = Q + ((size_t)b * TT + qrowL) * EE + h * 128;
    const short* qrpH = Q + ((size_t)b * TT + qrowH) * EE + h * 128;
    s16x8 qA1[2], qA2[2], qB1[2], qB2[2];
#pragma unroll
    for (int c = 0; c < 2; c++) {
      qA1[c] = *(const s16x8*)(qrpL + c * 32 + lg * 8);
      qA2[c] = *(const s16x8*)(qrpL + 64 + c * 32 + lg * 8);
      qB1[c] = *(const s16x8*)(qrpH + c * 32 + lg * 8);
      qB2[c] = *(const s16x8*)(qrpH + 64 + c * 32 + lg * 8);
    }

    const f32x4 zero = {0.f, 0.f, 0.f, 0.f};
    f32x4 o1L[8], o2L[8], o1H[8], o2H[8];
#pragma unroll
    for (int d = 0; d < 8; d++) { o1L[d] = zero; o2L[d] = zero; o1H[d] = zero; o2H[d] = zero; }
    float lp1L = 0.f, lp2L = 0.f, lp1H = 0.f, lp2H = 0.f;

    const int kvend = q0 + 32;
    for (int kv0 = wv * 32; kv0 < kvend; kv0 += 128) {
      // --- V B-fragments (shared by both q-halves): issue early ---
      s16x8 vbf[8];
#pragma unroll
      for (int d = 0; d < 8; d++)
        vbf[d] = *(const s16x8*)(VTh + (size_t)(d * 16 + lr) * TT + kv0 + lg * 8);

      // --- K A-fragments (shared); S^T for lo and hi halves ---
      f32x4 s1L[2], s2L[2], s1H[2], s2H[2];
#pragma unroll
      for (int kb = 0; kb < 2; kb++) {
        const short* krow = Kh + (size_t)(kv0 + kb * 16 + lr) * EE;
        s16x8 ka0 = *(const s16x8*)(krow + lg * 8);
        s16x8 ka1 = *(const s16x8*)(krow + 32 + lg * 8);
        s16x8 kb0 = *(const s16x8*)(krow + 64 + lg * 8);
        s16x8 kb1 = *(const s16x8*)(krow + 96 + lg * 8);
        f32x4 t;
        t = MFMA16(ka0, qA1[0], zero); t = MFMA16(ka1, qA1[1], t); s1L[kb] = t;
        t = MFMA16(kb0, qA2[0], zero); t = MFMA16(kb1, qA2[1], t); s2L[kb] = t;
        t = MFMA16(ka0, qB1[0], zero); t = MFMA16(ka1, qB1[1], t); s1H[kb] = t;
        t = MFMA16(kb0, qB2[0], zero); t = MFMA16(kb1, qB2[1], t); s2H[kb] = t;
      }

      // --- static-max softmax for both halves ---
      float p1L[8], p2L[8], p1H[8], p2H[8];
#pragma unroll
      for (int kb = 0; kb < 2; kb++)
#pragma unroll
        for (int r = 0; r < 4; r++) {
          int keyg = kv0 + kb * 16 + lg * 4 + r;
          bool okL = keyg <= qrowL, okH = keyg <= qrowH;
          float e1L = okL ? __expf(s1L[kb][r] * 0.125f) : 0.f;
          float e2L = okL ? __expf(s2L[kb][r] * 0.125f) : 0.f;
          float e1H = okH ? __expf(s1H[kb][r] * 0.125f) : 0.f;
          float e2H = okH ? __expf(s2H[kb][r] * 0.125f) : 0.f;
          p1L[kb * 4 + r] = e1L; p2L[kb * 4 + r] = e2L;
          p1H[kb * 4 + r] = e1H; p2H[kb * 4 + r] = e2H;
          lp1L += e1L; lp2L += e2L; lp1H += e1H; lp2H += e2H;
        }

      // --- pack+redistribute P -> PV A-fragments (both halves) ---
      const int srcbase = (lg & 1) * 32 + lr;
      const bool hi = (lg >= 2);
      union { unsigned w[4]; s16x8 v; } pa1L, pa2L, pa1H, pa2H;
      {
        unsigned u1[4], u2[4], u3[4], u4[4];
#pragma unroll
        for (int q = 0; q < 4; q++) {
          asm("v_cvt_pk_bf16_f32 %0, %1, %2" : "=v"(u1[q]) : "v"(p1L[2 * q]), "v"(p1L[2 * q + 1]));
          asm("v_cvt_pk_bf16_f32 %0, %1, %2" : "=v"(u2[q]) : "v"(p2L[2 * q]), "v"(p2L[2 * q + 1]));
          asm("v_cvt_pk_bf16_f32 %0, %1, %2" : "=v"(u3[q]) : "v"(p1H[2 * q]), "v"(p1H[2 * q + 1]));
          asm("v_cvt_pk_bf16_f32 %0, %1, %2" : "=v"(u4[q]) : "v"(p2H[2 * q]), "v"(p2H[2 * q + 1]));
        }
#pragma unroll
        for (int t = 0; t < 4; t++) {
          int src = srcbase + (t >> 1) * 16;
          unsigned a, bb2;
          a = __shfl(u1[t & 1], src); bb2 = __shfl(u1[2 + (t & 1)], src); pa1L.w[t] = hi ? bb2 : a;
          a = __shfl(u2[t & 1], src); bb2 = __shfl(u2[2 + (t & 1)], src); pa2L.w[t] = hi ? bb2 : a;
          a = __shfl(u3[t & 1], src); bb2 = __shfl(u3[2 + (t & 1)], src); pa1H.w[t] = hi ? bb2 : a;
          a = __shfl(u4[t & 1], src); bb2 = __shfl(u4[2 + (t & 1)], src); pa2H.w[t] = hi ? bb2 : a;
        }
      }

      // --- PV accumulate (shared vbf) ---
#pragma unroll
      for (int d = 0; d < 8; d++) {
        o1L[d] = MFMA16(pa1L.v, vbf[d], o1L[d]);
        o2L[d] = MFMA16(pa2L.v, vbf[d], o2L[d]);
        o1H[d] = MFMA16(pa1H.v, vbf[d], o1H[d]);
        o2H[d] = MFMA16(pa2H.v, vbf[d], o2H[d]);
      }
    }

    // --- cross-wave combine: waves 3->2->1->0, 4 planes ---
    for (int w = 3; w >= 1; --w) {
      if (wv == w) {
#pragma unroll
        for (int d = 0; d < 8; d++)
#pragma unroll
          for (int r = 0; r < 4; r++) {
            ob[0][lane * 33 + d * 4 + r] = o1L[d][r];
            ob[1][lane * 33 + d * 4 + r] = o2L[d][r];
            ob[2][lane * 33 + d * 4 + r] = o1H[d][r];
            ob[3][lane * 33 + d * 4 + r] = o2H[d][r];
          }
        lb[0][lane] = lp1L; lb[1][lane] = lp2L; lb[2][lane] = lp1H; lb[3][lane] = lp2H;
      }
      __syncthreads();
      if (wv == w - 1) {
#pragma unroll
        for (int d = 0; d < 8; d++)
#pragma unroll
          for (int r = 0; r < 4; r++) {
            o1L[d][r] += ob[0][lane * 33 + d * 4 + r];
            o2L[d][r] += ob[1][lane * 33 + d * 4 + r];
            o1H[d][r] += ob[2][lane * 33 + d * 4 + r];
            o2H[d][r] += ob[3][lane * 33 + d * 4 + r];
          }
        lp1L += lb[0][lane]; lp2L += lb[1][lane]; lp1H += lb[2][lane]; lp2H += lb[3][lane];
      }
      __syncthreads();
    }

    // --- epilogue (wave 0): both halves, r13-verbatim per half ---
    if (wv == 0) {
#pragma unroll
      for (int half = 0; half < 2; half++) {
        float l1 = half ? lp1H : lp1L, l2 = half ? lp2H : lp2L;
        f32x4* o1 = half ? o1H : o1L;
        f32x4* o2 = half ? o2H : o2L;
        const int rbase = q0 + half * 16;

        l1 += __shfl_xor(l1, 16); l1 += __shfl_xor(l1, 32);
        l2 += __shfl_xor(l2, 16); l2 += __shfl_xor(l2, 32);

        f32x4 i1, i2;
#pragma unroll
        for (int r = 0; r < 4; r++) {
          i1[r] = 1.f / __shfl(l1, lg * 4 + r);
          i2[r] = 1.f / __shfl(l2, lg * 4 + r);
        }
        f32x4 a[8];
        float ss[4] = {0.f, 0.f, 0.f, 0.f};
#pragma unroll
        for (int d = 0; d < 8; d++) {
          a[d] = o1[d] * i1 - (lam * o2[d]) * i2;
#pragma unroll
          for (int r = 0; r < 4; r++) ss[r] += a[d][r] * a[d][r];
        }
#pragma unroll
        for (int r = 0; r < 4; r++) {
          ss[r] += __shfl_xor(ss[r], 1);
          ss[r] += __shfl_xor(ss[r], 2);
          ss[r] += __shfl_xor(ss[r], 4);
          ss[r] += __shfl_xor(ss[r], 8);
        }
        f32x4 rs;
#pragma unroll
        for (int r = 0; r < 4; r++) rs[r] = rsqrtf(ss[r] * (1.f / 128.f) + 1e-5f) * ONE_MINUS_LI;
#pragma unroll
        for (int d = 0; d < 8; d++) {
          float gv = g[d * 16 + lr];
#pragma unroll
          for (int r = 0; r < 4; r++) {
            int row = rbase + lg * 4 + r;
            anorm[((size_t)b * TT + row) * 1024 + h * 128 + d * 16 + lr] = f2b(a[d][r] * rs[r] * gv);
          }
        }
      }
    }
    __syncthreads();  // wave0 epilogue done before next phase reuses ob/lb
  }
}

extern "C" void kernel_launch(void* const* d_in, const int* in_sizes, int n_in,
                              void* d_out, int out_size, void* d_ws, size_t ws_size,
                              hipStream_t stream) {
  const float* x   = (const float*)d_in[0];
  const float* wq  = (const float*)d_in[1];
  const float* wk  = (const float*)d_in[2];
  const float* wv  = (const float*)d_in[3];
  const float* wo  = (const float*)d_in[4];
  const float* lq1 = (const float*)d_in[5];
  const float* lk1 = (const float*)d_in[6];
  const float* lq2 = (const float*)d_in[7];
  const float* lk2 = (const float*)d_in[8];
  const float* g   = (const float*)d_in[9];

  // Workspace layout (40 MB + 4 B):
  //   [0,8)   MB : xb (bf16 x)  -- dead after gemm_qkv; reused as an
  //   [8,16)  MB : wT
  //   [16,24) MB : Qb   [24,32) MB : Kb
  //   [32,40) MB : VT (V written pre-transposed by gemm_qkv)
  //   40 MB       : lamf (4 B)
  char* ws = (char*)d_ws;
  short* xb  = (short*)(ws);
  short* wT  = (short*)(ws + ((size_t)8 << 20));
  short* Qb  = (short*)(ws + ((size_t)16 << 20));
  short* Kb  = (short*)(ws + ((size_t)24 << 20));
  short* VT  = (short*)(ws + ((size_t)32 << 20));
  short* an  = xb;  // alias: xb dead once gemm_qkv has consumed it
  float* lamf = (float*)(ws + ((size_t)40 << 20));

  cvt_x<<<4096, 256, 0, stream>>>(x, xb);
  transpose_w<<<dim3(32, 32, 4), dim3(32, 8), 0, stream>>>(wq, wk, wv, wo, wT);
  lam_kernel<<<1, 64, 0, stream>>>(lq1, lk1, lq2, lk2, lamf);
  gemm_qkv<<<dim3(32, 24), 256, 0, stream>>>(xb, wT, Qb, Kb, VT);
  attn_kernel<<<512, 256, 0, stream>>>(Qb, Kb, VT, lamf, g, an);
  gemm_out<<<dim3(32, 8), 256, 0, stream>>>(an, wT + (size_t)3 * EE * EE, (float*)d_out);
}

// Round 22
// 151.994 us; speedup vs baseline: 1.1756x; 1.0029x over previous
//
#include <hip/hip_runtime.h>
#include <hip/hip_bf16.h>

// Problem constants
#define BB 2
#define TT 2048
#define EE 1024
#define HH 8
// D = 64, 2D = 128 per head
#define LAMBDA_INIT 0.35550906759096928f
#define ONE_MINUS_LI 0.64449093240903072f

typedef short s16x8 __attribute__((ext_vector_type(8)));
typedef short s16x4 __attribute__((ext_vector_type(4)));
typedef float f32x4 __attribute__((ext_vector_type(4)));

#define MFMA16(a,b,c) __builtin_amdgcn_mfma_f32_16x16x32_bf16((a),(b),(c),0,0,0)

__device__ __forceinline__ short f2b(float f) {
  __hip_bfloat16 h = __float2bfloat16(f);
  return *reinterpret_cast<short*>(&h);
}

__device__ __forceinline__ void load_lds16(const void* g, void* l) {
  __builtin_amdgcn_global_load_lds(
      (const __attribute__((address_space(1))) unsigned int*)g,
      (__attribute__((address_space(3))) unsigned int*)l, 16, 0, 0);
}

// ---------------- x -> bf16 ----------------
__global__ __launch_bounds__(256) void cvt_x(const float* __restrict__ x, short* __restrict__ xb) {
  int i = blockIdx.x * 256 + threadIdx.x;
  float4 v = ((const float4*)x)[i];
  s16x4 s;
  s[0] = f2b(v.x); s[1] = f2b(v.y); s[2] = f2b(v.z); s[3] = f2b(v.w);
  ((s16x4*)xb)[i] = s;
}

// ---------------- weights -> bf16, transposed (wT[n][k]) ----------------
__global__ __launch_bounds__(256) void transpose_w(const float* __restrict__ wq, const float* __restrict__ wk,
                                                   const float* __restrict__ wv, const float* __restrict__ wo,
                                                   short* __restrict__ wT) {
  __shared__ float t[32][33];
  const int z = blockIdx.z;
  const float* src = (z == 0) ? wq : (z == 1) ? wk : (z == 2) ? wv : wo;
  const int nbase = blockIdx.x * 32, kbase = blockIdx.y * 32;
  const int tx = threadIdx.x, ty = threadIdx.y;
#pragma unroll
  for (int i = 0; i < 4; i++)
    t[ty + i * 8][tx] = src[(size_t)(kbase + ty + i * 8) * EE + nbase + tx];
  __syncthreads();
  short* dst = wT + (size_t)z * EE * EE;
#pragma unroll
  for (int i = 0; i < 4; i++)
    dst[(size_t)(nbase + ty + i * 8) * EE + kbase + tx] = f2b(t[tx][ty + i * 8]);
}

// ---------------- 128x128 bf16 MFMA GEMM core (K=1024, all strides 1024) ----------------
__device__ __forceinline__ void gemm_body(const short* __restrict__ A, const short* __restrict__ Bt,
                                          int row0, int col0, f32x4 acc[4][4],
                                          short* As, short* Bs) {
  const int tid = threadIdx.x, wv = tid >> 6, lane = tid & 63;
  const int lr = lane & 15, lg = lane >> 4;
  const int wr = wv >> 1, wc = wv & 1;
#pragma unroll
  for (int m = 0; m < 4; m++)
#pragma unroll
    for (int n = 0; n < 4; n++) acc[m][n] = (f32x4){0.f, 0.f, 0.f, 0.f};

  for (int kt = 0; kt < 1024; kt += 32) {
#pragma unroll
    for (int c = 0; c < 2; c++) {
      load_lds16((const char*)(A + (size_t)(row0 + wv * 32 + c * 16 + (lane >> 2)) * 1024 + kt) + (lane & 3) * 16,
                 (char*)As + (wv * 32 + c * 16) * 64 + lane * 16);
      load_lds16((const char*)(Bt + (size_t)(col0 + wv * 32 + c * 16 + (lane >> 2)) * 1024 + kt) + (lane & 3) * 16,
                 (char*)Bs + (wv * 32 + c * 16) * 64 + lane * 16);
    }
    __syncthreads();
    s16x8 af[4], bfr[4];
#pragma unroll
    for (int m = 0; m < 4; m++) af[m] = *(const s16x8*)&As[(wr * 64 + m * 16 + lr) * 32 + lg * 8];
#pragma unroll
    for (int n = 0; n < 4; n++) bfr[n] = *(const s16x8*)&Bs[(wc * 64 + n * 16 + lr) * 32 + lg * 8];
#pragma unroll
    for (int m = 0; m < 4; m++)
#pragma unroll
      for (int n = 0; n < 4; n++) acc[m][n] = MFMA16(af[m], bfr[n], acc[m][n]);
    __syncthreads();
  }
}

// QKV projection. Q,K row-major; V written DIRECTLY transposed as
// VT[(b*8+h)*128 + dim][token] (r21-green epilogue).
__global__ __launch_bounds__(256) void gemm_qkv(const short* __restrict__ xb, const short* __restrict__ wT,
                                                short* __restrict__ Qb, short* __restrict__ Kb,
                                                short* __restrict__ VT) {
  __shared__ short As[128 * 32];
  __shared__ short Bs[128 * 32];
  const int row0 = blockIdx.x * 128;
  const int wsel = blockIdx.y >> 3;
  const int col0 = (blockIdx.y & 7) * 128;
  const short* Bt = wT + (size_t)wsel * EE * EE;
  f32x4 acc[4][4];
  gemm_body(xb, Bt, row0, col0, acc, As, Bs);
  const int lane = threadIdx.x & 63, wv = threadIdx.x >> 6;
  const int lr = lane & 15, lg = lane >> 4, wr = wv >> 1, wc = wv & 1;
  if (wsel < 2) {
    short* outp = (wsel == 0) ? Qb : Kb;
#pragma unroll
    for (int m = 0; m < 4; m++)
#pragma unroll
      for (int n = 0; n < 4; n++)
#pragma unroll
        for (int r = 0; r < 4; r++) {
          int row = row0 + wr * 64 + m * 16 + lg * 4 + r;
          int col = col0 + wc * 64 + n * 16 + lr;
          outp[(size_t)row * 1024 + col] = f2b(acc[m][n][r]);
        }
  } else {
    // V: transpose on the fly. row -> (b, token), col -> (h, dim).
#pragma unroll
    for (int m = 0; m < 4; m++)
#pragma unroll
      for (int n = 0; n < 4; n++) {
        int row = row0 + wr * 64 + m * 16 + lg * 4;  // 4 consecutive tokens
        int col = col0 + wc * 64 + n * 16 + lr;
        int bq = row >> 11, tok = row & 2047;
        int hh = col >> 7, dim = col & 127;
        s16x4 s;
#pragma unroll
        for (int r = 0; r < 4; r++) s[r] = f2b(acc[m][n][r]);
        *(s16x4*)&VT[((size_t)(bq * 8 + hh) * 128 + dim) * 2048 + tok] = s;
      }
  }
}

// Output projection: anorm(4096x1024 bf16) @ wo -> d_out fp32
__global__ __launch_bounds__(256) void gemm_out(const short* __restrict__ an, const short* __restrict__ woT,
                                                float* __restrict__ C) {
  __shared__ short As[128 * 32];
  __shared__ short Bs[128 * 32];
  const int row0 = blockIdx.x * 128;
  const int col0 = blockIdx.y * 128;
  f32x4 acc[4][4];
  gemm_body(an, woT, row0, col0, acc, As, Bs);
  const int lane = threadIdx.x & 63, wv = threadIdx.x >> 6;
  const int lr = lane & 15, lg = lane >> 4, wr = wv >> 1, wc = wv & 1;
#pragma unroll
  for (int m = 0; m < 4; m++)
#pragma unroll
    for (int n = 0; n < 4; n++)
#pragma unroll
      for (int r = 0; r < 4; r++) {
        int row = row0 + wr * 64 + m * 16 + lg * 4 + r;
        int col = col0 + wc * 64 + n * 16 + lr;
        C[(size_t)row * 1024 + col] = acc[m][n][r];
      }
}

// ---------------- differential flash attention + RMS norm ----------------
// r21-green verbatim (2 q-halves/wave, complementary-pair 2-phase, 4-wave
// kv-split, static-max). ONLY change: lambda computed in-kernel (same
// shfl_xor reduction order as the old lam_kernel -> bitwise-identical lam);
// lam_kernel launch and lamf buffer removed.
__global__ __launch_bounds__(256, 2) void attn_kernel(const short* __restrict__ Q, const short* __restrict__ K,
                                                      const short* __restrict__ VT,
                                                      const float* __restrict__ lq1, const float* __restrict__ lk1,
                                                      const float* __restrict__ lq2, const float* __restrict__ lk2,
                                                      const float* __restrict__ g, short* __restrict__ anorm) {
  __shared__ float ob[4][64 * 33];  // 4 planes (o1L,o2L,o1H,o2H), stride 33
  __shared__ float lb[4][64];

  const int bid = blockIdx.x;
  const int xcd = bid & 7, slot2 = bid >> 3;         // 64 slots x 8 xcd
  const int bh = xcd + (slot2 >> 5) * 8;             // 2 bh per xcd
  const int pair = slot2 & 31;                       // 32 complementary pairs
  const int b = bh >> 3, h = bh & 7;

  const int tid = threadIdx.x, wv = tid >> 6, lane = tid & 63;
  const int lr = lane & 15, lg = lane >> 4;

  // --- lambda (fused; identical reduction order as old lam_kernel) ---
  float lam;
  {
    float p1 = lq1[lane] * lk1[lane];
    float p2 = lq2[lane] * lk2[lane];
#pragma unroll
    for (int m = 1; m <= 32; m <<= 1) { p1 += __shfl_xor(p1, m); p2 += __shfl_xor(p2, m); }
    lam = __expf(p1) - __expf(p2) + LAMBDA_INIT;
  }

  const short* Kh = K + (size_t)b * TT * EE + h * 128;
  const short* VTh = VT + (size_t)bh * 128 * TT;

  for (int phase = 0; phase < 2; phase++) {
    const int qt = phase == 0 ? (63 - pair) : pair;  // long tile first
    const int q0 = qt * 32;
    const int qrowL = q0 + lr, qrowH = q0 + 16 + lr;

    // Q fragments for both q-halves (B-operand: col=lr)
    const short* qrpL = Q + ((size_t)b * TT + qrowL) * EE + h * 128;
    const short* qrpH = Q + ((size_t)b * TT + qrowH) * EE + h * 128;
    s16x8 qA1[2], qA2[2], qB1[2], qB2[2];
#pragma unroll
    for (int c = 0; c < 2; c++) {
      qA1[c] = *(const s16x8*)(qrpL + c * 32 + lg * 8);
      qA2[c] = *(const s16x8*)(qrpL + 64 + c * 32 + lg * 8);
      qB1[c] = *(const s16x8*)(qrpH + c * 32 + lg * 8);
      qB2[c] = *(const s16x8*)(qrpH + 64 + c * 32 + lg * 8);
    }

    const f32x4 zero = {0.f, 0.f, 0.f, 0.f};
    f32x4 o1L[8], o2L[8], o1H[8], o2H[8];
#pragma unroll
    for (int d = 0; d < 8; d++) { o1L[d] = zero; o2L[d] = zero; o1H[d] = zero; o2H[d] = zero; }
    float lp1L = 0.f, lp2L = 0.f, lp1H = 0.f, lp2H = 0.f;

    const int kvend = q0 + 32;
    for (int kv0 = wv * 32; kv0 < kvend; kv0 += 128) {
      // --- V B-fragments (shared by both q-halves): issue early ---
      s16x8 vbf[8];
#pragma unroll
      for (int d = 0; d < 8; d++)
        vbf[d] = *(const s16x8*)(VTh + (size_t)(d * 16 + lr) * TT + kv0 + lg * 8);

      // --- K A-fragments (shared); S^T for lo and hi halves ---
      f32x4 s1L[2], s2L[2], s1H[2], s2H[2];
#pragma unroll
      for (int kb = 0; kb < 2; kb++) {
        const short* krow = Kh + (size_t)(kv0 + kb * 16 + lr) * EE;
        s16x8 ka0 = *(const s16x8*)(krow + lg * 8);
        s16x8 ka1 = *(const s16x8*)(krow + 32 + lg * 8);
        s16x8 kb0 = *(const s16x8*)(krow + 64 + lg * 8);
        s16x8 kb1 = *(const s16x8*)(krow + 96 + lg * 8);
        f32x4 t;
        t = MFMA16(ka0, qA1[0], zero); t = MFMA16(ka1, qA1[1], t); s1L[kb] = t;
        t = MFMA16(kb0, qA2[0], zero); t = MFMA16(kb1, qA2[1], t); s2L[kb] = t;
        t = MFMA16(ka0, qB1[0], zero); t = MFMA16(ka1, qB1[1], t); s1H[kb] = t;
        t = MFMA16(kb0, qB2[0], zero); t = MFMA16(kb1, qB2[1], t); s2H[kb] = t;
      }

      // --- static-max softmax for both halves ---
      float p1L[8], p2L[8], p1H[8], p2H[8];
#pragma unroll
      for (int kb = 0; kb < 2; kb++)
#pragma unroll
        for (int r = 0; r < 4; r++) {
          int keyg = kv0 + kb * 16 + lg * 4 + r;
          bool okL = keyg <= qrowL, okH = keyg <= qrowH;
          float e1L = okL ? __expf(s1L[kb][r] * 0.125f) : 0.f;
          float e2L = okL ? __expf(s2L[kb][r] * 0.125f) : 0.f;
          float e1H = okH ? __expf(s1H[kb][r] * 0.125f) : 0.f;
          float e2H = okH ? __expf(s2H[kb][r] * 0.125f) : 0.f;
          p1L[kb * 4 + r] = e1L; p2L[kb * 4 + r] = e2L;
          p1H[kb * 4 + r] = e1H; p2H[kb * 4 + r] = e2H;
          lp1L += e1L; lp2L += e2L; lp1H += e1H; lp2H += e2H;
        }

      // --- pack+redistribute P -> PV A-fragments (both halves) ---
      const int srcbase = (lg & 1) * 32 + lr;
      const bool hi = (lg >= 2);
      union { unsigned w[4]; s16x8 v; } pa1L, pa2L, pa1H, pa2H;
      {
        unsigned u1[4], u2[4], u3[4], u4[4];
#pragma unroll
        for (int q = 0; q < 4; q++) {
          asm("v_cvt_pk_bf16_f32 %0, %1, %2" : "=v"(u1[q]) : "v"(p1L[2 * q]), "v"(p1L[2 * q + 1]));
          asm("v_cvt_pk_bf16_f32 %0, %1, %2" : "=v"(u2[q]) : "v"(p2L[2 * q]), "v"(p2L[2 * q + 1]));
          asm("v_cvt_pk_bf16_f32 %0, %1, %2" : "=v"(u3[q]) : "v"(p1H[2 * q]), "v"(p1H[2 * q + 1]));
          asm("v_cvt_pk_bf16_f32 %0, %1, %2" : "=v"(u4[q]) : "v"(p2H[2 * q]), "v"(p2H[2 * q + 1]));
        }
#pragma unroll
        for (int t = 0; t < 4; t++) {
          int src = srcbase + (t >> 1) * 16;
          unsigned a, bb2;
          a = __shfl(u1[t & 1], src); bb2 = __shfl(u1[2 + (t & 1)], src); pa1L.w[t] = hi ? bb2 : a;
          a = __shfl(u2[t & 1], src); bb2 = __shfl(u2[2 + (t & 1)], src); pa2L.w[t] = hi ? bb2 : a;
          a = __shfl(u3[t & 1], src); bb2 = __shfl(u3[2 + (t & 1)], src); pa1H.w[t] = hi ? bb2 : a;
          a = __shfl(u4[t & 1], src); bb2 = __shfl(u4[2 + (t & 1)], src); pa2H.w[t] = hi ? bb2 : a;
        }
      }

      // --- PV accumulate (shared vbf) ---
#pragma unroll
      for (int d = 0; d < 8; d++) {
        o1L[d] = MFMA16(pa1L.v, vbf[d], o1L[d]);
        o2L[d] = MFMA16(pa2L.v, vbf[d], o2L[d]);
        o1H[d] = MFMA16(pa1H.v, vbf[d], o1H[d]);
        o2H[d] = MFMA16(pa2H.v, vbf[d], o2H[d]);
      }
    }

    // --- cross-wave combine: waves 3->2->1->0, 4 planes ---
    for (int w = 3; w >= 1; --w) {
      if (wv == w) {
#pragma unroll
        for (int d = 0; d < 8; d++)
#pragma unroll
          for (int r = 0; r < 4; r++) {
            ob[0][lane * 33 + d * 4 + r] = o1L[d][r];
            ob[1][lane * 33 + d * 4 + r] = o2L[d][r];
            ob[2][lane * 33 + d * 4 + r] = o1H[d][r];
            ob[3][lane * 33 + d * 4 + r] = o2H[d][r];
          }
        lb[0][lane] = lp1L; lb[1][lane] = lp2L; lb[2][lane] = lp1H; lb[3][lane] = lp2H;
      }
      __syncthreads();
      if (wv == w - 1) {
#pragma unroll
        for (int d = 0; d < 8; d++)
#pragma unroll
          for (int r = 0; r < 4; r++) {
            o1L[d][r] += ob[0][lane * 33 + d * 4 + r];
            o2L[d][r] += ob[1][lane * 33 + d * 4 + r];
            o1H[d][r] += ob[2][lane * 33 + d * 4 + r];
            o2H[d][r] += ob[3][lane * 33 + d * 4 + r];
          }
        lp1L += lb[0][lane]; lp2L += lb[1][lane]; lp1H += lb[2][lane]; lp2H += lb[3][lane];
      }
      __syncthreads();
    }

    // --- epilogue (wave 0): both halves, r13-verbatim per half ---
    if (wv == 0) {
#pragma unroll
      for (int half = 0; half < 2; half++) {
        float l1 = half ? lp1H : lp1L, l2 = half ? lp2H : lp2L;
        f32x4* o1 = half ? o1H : o1L;
        f32x4* o2 = half ? o2H : o2L;
        const int rbase = q0 + half * 16;

        l1 += __shfl_xor(l1, 16); l1 += __shfl_xor(l1, 32);
        l2 += __shfl_xor(l2, 16); l2 += __shfl_xor(l2, 32);

        f32x4 i1, i2;
#pragma unroll
        for (int r = 0; r < 4; r++) {
          i1[r] = 1.f / __shfl(l1, lg * 4 + r);
          i2[r] = 1.f / __shfl(l2, lg * 4 + r);
        }
        f32x4 a[8];
        float ss[4] = {0.f, 0.f, 0.f, 0.f};
#pragma unroll
        for (int d = 0; d < 8; d++) {
          a[d] = o1[d] * i1 - (lam * o2[d]) * i2;
#pragma unroll
          for (int r = 0; r < 4; r++) ss[r] += a[d][r] * a[d][r];
        }
#pragma unroll
        for (int r = 0; r < 4; r++) {
          ss[r] += __shfl_xor(ss[r], 1);
          ss[r] += __shfl_xor(ss[r], 2);
          ss[r] += __shfl_xor(ss[r], 4);
          ss[r] += __shfl_xor(ss[r], 8);
        }
        f32x4 rs;
#pragma unroll
        for (int r = 0; r < 4; r++) rs[r] = rsqrtf(ss[r] * (1.f / 128.f) + 1e-5f) * ONE_MINUS_LI;
#pragma unroll
        for (int d = 0; d < 8; d++) {
          float gv = g[d * 16 + lr];
#pragma unroll
          for (int r = 0; r < 4; r++) {
            int row = rbase + lg * 4 + r;
            anorm[((size_t)b * TT + row) * 1024 + h * 128 + d * 16 + lr] = f2b(a[d][r] * rs[r] * gv);
          }
        }
      }
    }
    __syncthreads();  // wave0 epilogue done before next phase reuses ob/lb
  }
}

extern "C" void kernel_launch(void* const* d_in, const int* in_sizes, int n_in,
                              void* d_out, int out_size, void* d_ws, size_t ws_size,
                              hipStream_t stream) {
  const float* x   = (const float*)d_in[0];
  const float* wq  = (const float*)d_in[1];
  const float* wk  = (const float*)d_in[2];
  const float* wv  = (const float*)d_in[3];
  const float* wo  = (const float*)d_in[4];
  const float* lq1 = (const float*)d_in[5];
  const float* lk1 = (const float*)d_in[6];
  const float* lq2 = (const float*)d_in[7];
  const float* lk2 = (const float*)d_in[8];
  const float* g   = (const float*)d_in[9];

  // Workspace layout (40 MB):
  //   [0,8)   MB : xb (bf16 x)  -- dead after gemm_qkv; reused as an
  //   [8,16)  MB : wT
  //   [16,24) MB : Qb   [24,32) MB : Kb
  //   [32,40) MB : VT (V written pre-transposed by gemm_qkv)
  char* ws = (char*)d_ws;
  short* xb  = (short*)(ws);
  short* wT  = (short*)(ws + ((size_t)8 << 20));
  short* Qb  = (short*)(ws + ((size_t)16 << 20));
  short* Kb  = (short*)(ws + ((size_t)24 << 20));
  short* VT  = (short*)(ws + ((size_t)32 << 20));
  short* an  = xb;  // alias: xb dead once gemm_qkv has consumed it

  cvt_x<<<4096, 256, 0, stream>>>(x, xb);
  transpose_w<<<dim3(32, 32, 4), dim3(32, 8), 0, stream>>>(wq, wk, wv, wo, wT);
  gemm_qkv<<<dim3(32, 24), 256, 0, stream>>>(xb, wT, Qb, Kb, VT);
  attn_kernel<<<512, 256, 0, stream>>>(Qb, Kb, VT, lq1, lk1, lq2, lk2, g, an);
  gemm_out<<<dim3(32, 8), 256, 0, stream>>>(an, wT + (size_t)3 * EE * EE, (float*)d_out);
}